// Round 6
// baseline (478.281 us; speedup 1.0000x reference)
//
#include <hip/hip_runtime.h>

#define D 64
#define SH 8   // XCD shards

typedef unsigned long long u64;

// ---------------------------------------------------------------------------
// K0: Ttw[which][j] = sum_k tw[a][k] * W[base+k][j]  for both layers
// which: 0=row/a0, 1=row/a1 (W rows 64..127), 2=col/a0, 3=col/a1 (rows 192..255)
// ---------------------------------------------------------------------------
__global__ __launch_bounds__(256) void k_ttw(
    const float* __restrict__ tw1, const float* __restrict__ W1, float* __restrict__ T1,
    const float* __restrict__ tw2, const float* __restrict__ W2, float* __restrict__ T2)
{
    const float* tw = blockIdx.x ? tw2 : tw1;
    const float* W  = blockIdx.x ? W2  : W1;
    float*       T  = blockIdx.x ? T2  : T1;
    int t = threadIdx.x;
    int j = t & 63;
    int which = t >> 6;
    int a = which & 1;
    int base = (which < 2) ? 64 : 192;
    float s = 0.f;
    #pragma unroll 8
    for (int k = 0; k < 64; ++k)
        s += tw[a * 64 + k] * W[(base + k) * 64 + j];
    T[which * 64 + j] = s;
}

// ---------------------------------------------------------------------------
// K1: per-(shard,node) packed count+label atomic. Shard = edge position / SH_SZ,
// and block b handles shard b%8 -> (round-robin dispatch) all atomics on slice
// s come from XCD s -> lines stay in that XCD's L2. Fields [cnt:10|q0:27|q1:27],
// labels quantized at 2^16; per-shard sums can't overflow fields.
// ---------------------------------------------------------------------------
__global__ __launch_bounds__(256) void k_count(
    const int* __restrict__ row, const int* __restrict__ col,
    const float* __restrict__ el,
    u64* __restrict__ packR, u64* __restrict__ packC, int E, int N, int SH_SZ)
{
    int s = blockIdx.x & (SH - 1);
    int j = blockIdx.x >> 3;
    int ebase = s * SH_SZ;
    int ssz = min(SH_SZ, E - ebase);
    int idx = j * 256 + threadIdx.x;
    if (idx >= ssz) return;
    int e = ebase + idx;
    int r = row[e], c = col[e];
    float2 lab = ((const float2*)el)[e];
    u64 q0 = (u64)(unsigned)(lab.x * 65536.0f);
    u64 q1 = (u64)(unsigned)(lab.y * 65536.0f);
    u64 p = (1ULL << 54) | (q0 << 27) | q1;
    atomicAdd(&packR[(size_t)s * N + r], p);
    atomicAdd(&packC[(size_t)s * N + c], p);
}

// ---------------------------------------------------------------------------
// K2: per-shard segment allocation (16 wave-scans + global cursors), deg-packs,
// stats. curX[s][n] = absolute start slot of node n's segment in shard s.
// ---------------------------------------------------------------------------
__global__ __launch_bounds__(256) void k_prep(
    const u64* __restrict__ packR, const u64* __restrict__ packC,
    int* __restrict__ curR, int* __restrict__ curC,
    u64* __restrict__ degpackR, u64* __restrict__ degpackC,
    float* __restrict__ stats, int* __restrict__ gcur, int N, int SH_SZ)
{
    int n = blockIdx.x * 256 + threadIdx.x;
    int lane = threadIdx.x & 63;
    const u64 LOW54 = (1ULL << 54) - 1;
    int cr[SH], cc[SH];
    u64 TR = 0, TC = 0;
    #pragma unroll
    for (int s = 0; s < SH; ++s) {
        u64 pR = (n < N) ? packR[(size_t)s * N + n] : 0;
        u64 pC = (n < N) ? packC[(size_t)s * N + n] : 0;
        cr[s] = (int)(pR >> 54); TR += pR & LOW54;
        cc[s] = (int)(pC >> 54); TC += pC & LOW54;
    }
    u64 dpR = 0, dpC = 0;
    int tr = 0, tc = 0;
    #pragma unroll
    for (int s = 0; s < SH; ++s) {
        int v = cr[s], ps = v;
        #pragma unroll
        for (int d = 1; d < 64; d <<= 1) { int t = __shfl_up(ps, d); if (lane >= d) ps += t; }
        int tot = __shfl(ps, 63);
        int b = 0;
        if (lane == 63) b = atomicAdd(&gcur[s], tot);
        b = __shfl(b, 63);
        if (n < N) curR[(size_t)s * N + n] = s * SH_SZ + b + ps - v;

        int v2 = cc[s], ps2 = v2;
        #pragma unroll
        for (int d = 1; d < 64; d <<= 1) { int t = __shfl_up(ps2, d); if (lane >= d) ps2 += t; }
        int tot2 = __shfl(ps2, 63);
        int b2 = 0;
        if (lane == 63) b2 = atomicAdd(&gcur[SH + s], tot2);
        b2 = __shfl(b2, 63);
        if (n < N) curC[(size_t)s * N + n] = s * SH_SZ + b2 + ps2 - v2;

        dpR |= ((u64)v)  << (8 * s); tr += v;
        dpC |= ((u64)v2) << (8 * s); tc += v2;
    }
    if (n < N) {
        degpackR[n] = dpR;
        degpackC[n] = dpC;
        const u64 M27 = (1ULL << 27) - 1;
        const float qs = 1.0f / 65536.0f;
        float sr0 = (float)((TR >> 27) & M27) * qs;
        float sr1 = (float)(TR & M27) * qs;
        float sc0 = (float)((TC >> 27) & M27) * qs;
        float sc1 = (float)(TC & M27) * qs;
        float ir = 1.0f / fmaxf((float)tr, 1.0f);
        float ic = 1.0f / fmaxf((float)tc, 1.0f);
        float* sN = stats + (size_t)n * 8;
        sN[0] = ir;        sN[1] = ic;
        sN[2] = sr0 * ir;  sN[3] = sr1 * ir;
        sN[4] = sc0 * ic;  sN[5] = sc1 * ic;
        sN[6] = (float)tr; sN[7] = (float)tc;
    }
}

// ---------------------------------------------------------------------------
// K3: sharded bucket fill. Shard s's cursor slice AND staging region are only
// touched by XCD s -> stores and atomics stay in local L2 (no line ping-pong).
// ---------------------------------------------------------------------------
__global__ __launch_bounds__(256) void k_fill(
    const int* __restrict__ row, const int* __restrict__ col,
    int* __restrict__ curR, int* __restrict__ curC,
    int* __restrict__ stageR, int* __restrict__ stageC, int E, int N, int SH_SZ)
{
    int s = blockIdx.x & (SH - 1);
    int j = blockIdx.x >> 3;
    int ebase = s * SH_SZ;
    int ssz = min(SH_SZ, E - ebase);
    int idx = j * 256 + threadIdx.x;
    if (idx >= ssz) return;
    int e = ebase + idx;
    int r = row[e], c = col[e];
    stageR[atomicAdd(&curR[(size_t)s * N + r], 1)] = c;
    stageC[atomicAdd(&curC[(size_t)s * N + c], 1)] = r;
}

// ---------------------------------------------------------------------------
// 8-segment gather for one node/side: branchless prefix-select over shards.
// post-fill cur[s][n] = seg_start + deg  ->  start = cur - deg.
// All small arrays indexed only in unrolled loops (stay in registers).
// ---------------------------------------------------------------------------
__device__ __forceinline__ float4 gather_side(
    const int* __restrict__ stage, const int* __restrict__ cur, u64 dp,
    int n, int N, const float4* __restrict__ x4, int grp, int c4)
{
    int d[SH], p[SH], st[SH];
    #pragma unroll
    for (int s = 0; s < SH; ++s) d[s] = (int)((dp >> (8 * s)) & 255);
    p[0] = 0;
    #pragma unroll
    for (int s = 1; s < SH; ++s) p[s] = p[s - 1] + d[s - 1];
    int deg = p[SH - 1] + d[SH - 1];
    #pragma unroll
    for (int s = 0; s < SH; ++s)
        st[s] = cur[(size_t)s * N + n] - d[s] - p[s];   // stadj: addr = st[s] + kk

    float4 acc = make_float4(0.f, 0.f, 0.f, 0.f);
    for (int k = 0; k < deg; k += 4) {
        int kk = k + grp;
        int addr = st[0] + kk;
        #pragma unroll
        for (int s = 1; s < SH; ++s)
            addr = (kk >= p[s]) ? st[s] + kk : addr;
        bool pv = kk < deg;
        int a = stage[pv ? addr : 0];
        float4 v = x4[(size_t)a * 16 + c4];
        if (pv) { acc.x += v.x; acc.y += v.y; acc.z += v.z; acc.w += v.w; }
    }
    return acc;
}

// ---------------------------------------------------------------------------
// K4: fused layer. 512 threads, 16 nodes/block, 2 nodes/wave. Gather via
// float4 (4 neighbors/wave-instr) from sharded CSR; cross-group shfl reduce.
// Phase B: h[128] @ W + rank-2 opinion epilogue. LDS 40KB -> 32 waves/CU.
// ---------------------------------------------------------------------------
__global__ __launch_bounds__(512) void k_layer(
    const float* __restrict__ x,
    const int* __restrict__ curR, const int* __restrict__ curC,
    const int* __restrict__ stageR, const int* __restrict__ stageC,
    const u64* __restrict__ degpackR, const u64* __restrict__ degpackC,
    const float* __restrict__ stats,
    const float* __restrict__ Ttw,   // [4][64]
    const float* __restrict__ W,     // [256][64]
    const float* __restrict__ b,     // [64]
    float* __restrict__ y, int N)
{
    __shared__ float4 hs4[16][32];
    __shared__ float  Ws[128 * 64];

    const float4* x4 = (const float4*)x;

    int t    = threadIdx.x;
    int lane = t & 63;
    int wv   = t >> 6;        // 0..7
    int c4   = lane & 15;
    int grp  = lane >> 4;     // 0..3
    int base = blockIdx.x * 16;

    float sf[2][4];

    #pragma unroll
    for (int i = 0; i < 2; ++i) {
        int loc = wv * 2 + i;
        int n   = base + loc;
        float4 accR = make_float4(0.f, 0.f, 0.f, 0.f);
        float4 accC = make_float4(0.f, 0.f, 0.f, 0.f);
        float ir = 0.f, ic = 0.f;
        sf[i][0] = sf[i][1] = sf[i][2] = sf[i][3] = 0.f;
        if (n < N) {
            const float4* st = (const float4*)(stats + (size_t)n * 8);
            float4 sA = st[0];
            float4 sB = st[1];
            ir = sA.x; ic = sA.y;
            sf[i][0] = sA.z; sf[i][1] = sA.w;
            sf[i][2] = sB.x; sf[i][3] = sB.y;
            accR = gather_side(stageR, curR, degpackR[n], n, N, x4, grp, c4);
            accC = gather_side(stageC, curC, degpackC[n], n, N, x4, grp, c4);
        }
        #pragma unroll
        for (int o = 16; o < 64; o <<= 1) {
            accR.x += __shfl_xor(accR.x, o); accR.y += __shfl_xor(accR.y, o);
            accR.z += __shfl_xor(accR.z, o); accR.w += __shfl_xor(accR.w, o);
            accC.x += __shfl_xor(accC.x, o); accC.y += __shfl_xor(accC.y, o);
            accC.z += __shfl_xor(accC.z, o); accC.w += __shfl_xor(accC.w, o);
        }
        if (grp == 0) {
            hs4[loc][c4]      = make_float4(accR.x * ir, accR.y * ir, accR.z * ir, accR.w * ir);
            hs4[loc][16 + c4] = make_float4(accC.x * ic, accC.y * ic, accC.z * ic, accC.w * ic);
        }
    }

    __syncthreads();
    #pragma unroll
    for (int i = 0; i < 16; ++i) {
        int L = i * 512 + t;
        Ws[L] = W[L + ((L < 4096) ? 0 : 4096)];
    }
    __syncthreads();

    const float* hsf = (const float*)hs4;
    int r0 = (wv * 2) * 128, r1 = r0 + 128;
    float a0 = 0.f, a1 = 0.f;
    #pragma unroll 8
    for (int j = 0; j < 128; ++j) {
        float wj = Ws[j * 64 + lane];
        a0 += hsf[r0 + j] * wj;
        a1 += hsf[r1 + j] * wj;
    }

    float tR0 = Ttw[lane],       tR1 = Ttw[64 + lane];
    float tC0 = Ttw[128 + lane], tC1 = Ttw[192 + lane];
    float bias = b[lane];
    float vv[2] = {a0, a1};
    #pragma unroll
    for (int i = 0; i < 2; ++i) {
        int n = base + wv * 2 + i;
        if (n < N) {
            float v = vv[i] + sf[i][0] * tR0 + sf[i][1] * tR1
                            + sf[i][2] * tC0 + sf[i][3] * tC1 + bias;
            y[(size_t)n * D + lane] = fmaxf(v, 0.0f);
        }
    }
}

// ---------------------------------------------------------------------------
extern "C" void kernel_launch(void* const* d_in, const int* in_sizes, int n_in,
                              void* d_out, int out_size, void* d_ws, size_t ws_size,
                              hipStream_t stream)
{
    const float* X   = (const float*)d_in[0];
    const int*   ei  = (const int*)  d_in[1];
    const float* el  = (const float*)d_in[2];
    const float* w1  = (const float*)d_in[3];
    const float* tw1 = (const float*)d_in[4];
    const float* b1  = (const float*)d_in[5];
    const float* w2  = (const float*)d_in[6];
    const float* tw2 = (const float*)d_in[7];
    const float* b2  = (const float*)d_in[8];
    float* out = (float*)d_out;

    int N = in_sizes[0] / D;     // 50000
    int E = in_sizes[1] / 2;     // 800000
    const int* row = ei;
    const int* col = ei + E;
    int SH_SZ = (E + SH - 1) / SH;

    // Workspace (~24.8 MB). pack region is reused as the staging CSR after
    // k_prep (pack is dead once degpack/cur/stats are built).
    size_t packBytes = (size_t)2 * SH * N * sizeof(u64);
    size_t stageBytes = (size_t)2 * E * sizeof(int);
    if (stageBytes > packBytes) packBytes = stageBytes;

    char* wsb = (char*)d_ws;
    u64*   packR    = (u64*)wsb;                        // SH*N u64 (zeroed)
    u64*   packC    = packR + (size_t)SH * N;           // SH*N u64 (zeroed)
    int*   stageR   = (int*)wsb;                        // E ints  (aliases pack)
    int*   stageC   = stageR + E;                       // E ints
    int*   gcur     = (int*)(wsb + packBytes);          // 32 ints (zeroed)
    int*   curR     = gcur + 32;                        // SH*N
    int*   curC     = curR + (size_t)SH * N;            // SH*N
    u64*   degpackR = (u64*)(curC + (size_t)SH * N);    // N
    u64*   degpackC = degpackR + N;                     // N
    float* stats    = (float*)(degpackC + N);           // 8N
    float* Ttw1     = stats + (size_t)8 * N;            // 256
    float* Ttw2     = Ttw1 + 256;                       // 256
    float* h1       = Ttw2 + 256;                       // 64N

    (void)hipMemsetAsync(packR, 0, (size_t)2 * SH * N * sizeof(u64), stream);
    (void)hipMemsetAsync(gcur, 0, 32 * sizeof(int), stream);

    k_ttw<<<2, 256, 0, stream>>>(tw1, w1, Ttw1, tw2, w2, Ttw2);

    int SB = SH * ((SH_SZ + 255) / 256);
    int NB = (N + 255) / 256;
    int LB = (N + 15) / 16;

    k_count<<<SB, 256, 0, stream>>>(row, col, el, packR, packC, E, N, SH_SZ);
    k_prep<<<NB, 256, 0, stream>>>(packR, packC, curR, curC,
                                   degpackR, degpackC, stats, gcur, N, SH_SZ);
    k_fill<<<SB, 256, 0, stream>>>(row, col, curR, curC, stageR, stageC, E, N, SH_SZ);

    k_layer<<<LB, 512, 0, stream>>>(X, curR, curC, stageR, stageC,
                                    degpackR, degpackC, stats,
                                    Ttw1, w1, b1, h1, N);
    k_layer<<<LB, 512, 0, stream>>>(h1, curR, curC, stageR, stageC,
                                    degpackR, degpackC, stats,
                                    Ttw2, w2, b2, out, N);
}

// Round 7
// 339.393 us; speedup vs baseline: 1.4092x; 1.4092x over previous
//
#include <hip/hip_runtime.h>

#define D 64
#define SH 8   // XCD shards

typedef unsigned long long u64;

// ---------------------------------------------------------------------------
// K0: Ttw[which][j] = sum_k tw[a][k] * W[base+k][j]  for both layers
// ---------------------------------------------------------------------------
__global__ __launch_bounds__(256) void k_ttw(
    const float* __restrict__ tw1, const float* __restrict__ W1, float* __restrict__ T1,
    const float* __restrict__ tw2, const float* __restrict__ W2, float* __restrict__ T2)
{
    const float* tw = blockIdx.x ? tw2 : tw1;
    const float* W  = blockIdx.x ? W2  : W1;
    float*       T  = blockIdx.x ? T2  : T1;
    int t = threadIdx.x;
    int j = t & 63;
    int which = t >> 6;
    int a = which & 1;
    int base = (which < 2) ? 64 : 192;
    float s = 0.f;
    #pragma unroll 8
    for (int k = 0; k < 64; ++k)
        s += tw[a * 64 + k] * W[(base + k) * 64 + j];
    T[which * 64 + j] = s;
}

// ---------------------------------------------------------------------------
// K1: per-(shard,node) packed count+label atomic; shard = e/SH_SZ handled by
// blocks with blockIdx%8==s -> XCD-local atomic lines. [cnt:10|q0:27|q1:27]
// ---------------------------------------------------------------------------
__global__ __launch_bounds__(256) void k_count(
    const int* __restrict__ row, const int* __restrict__ col,
    const float* __restrict__ el,
    u64* __restrict__ packR, u64* __restrict__ packC, int E, int N, int SH_SZ)
{
    int s = blockIdx.x & (SH - 1);
    int j = blockIdx.x >> 3;
    int ebase = s * SH_SZ;
    int ssz = min(SH_SZ, E - ebase);
    int idx = j * 256 + threadIdx.x;
    if (idx >= ssz) return;
    int e = ebase + idx;
    int r = row[e], c = col[e];
    float2 lab = ((const float2*)el)[e];
    u64 q0 = (u64)(unsigned)(lab.x * 65536.0f);
    u64 q1 = (u64)(unsigned)(lab.y * 65536.0f);
    u64 p = (1ULL << 54) | (q0 << 27) | q1;
    atomicAdd(&packR[(size_t)s * N + r], p);
    atomicAdd(&packC[(size_t)s * N + c], p);
}

// ---------------------------------------------------------------------------
// K2: per-shard segment allocation. 16 wave-scans (VALU), then ONE parallel
// atomic round per block: wave totals -> LDS, wave0 lanes 0..15 atomicAdd
// block totals on 16 line-padded counters simultaneously, bases -> LDS.
// Emits sub-cursors for k_fill, degree-packs, stats.
// ---------------------------------------------------------------------------
__global__ __launch_bounds__(256) void k_prep(
    const u64* __restrict__ packR, const u64* __restrict__ packC,
    int* __restrict__ curR, int* __restrict__ curC,
    u64* __restrict__ degpackR, u64* __restrict__ degpackC,
    float* __restrict__ stats, int* __restrict__ gcur, int N, int SH_SZ)
{
    __shared__ int lds_tot[4][16];
    __shared__ int lds_base[4][16];

    int n = blockIdx.x * 256 + threadIdx.x;
    int lane = threadIdx.x & 63;
    int wv = threadIdx.x >> 6;
    const u64 LOW54 = (1ULL << 54) - 1;
    int cr[SH], cc[SH], psR[SH], psC[SH];
    u64 TR = 0, TC = 0;
    #pragma unroll
    for (int s = 0; s < SH; ++s) {
        u64 pR = (n < N) ? packR[(size_t)s * N + n] : 0;
        u64 pC = (n < N) ? packC[(size_t)s * N + n] : 0;
        cr[s] = (int)(pR >> 54); TR += pR & LOW54;
        cc[s] = (int)(pC >> 54); TC += pC & LOW54;
    }
    // 16 wave-inclusive scans (register/shfl only)
    #pragma unroll
    for (int s = 0; s < SH; ++s) {
        int ps = cr[s];
        #pragma unroll
        for (int d2 = 1; d2 < 64; d2 <<= 1) { int t2 = __shfl_up(ps, d2); if (lane >= d2) ps += t2; }
        psR[s] = ps;
        int ps2 = cc[s];
        #pragma unroll
        for (int d2 = 1; d2 < 64; d2 <<= 1) { int t2 = __shfl_up(ps2, d2); if (lane >= d2) ps2 += t2; }
        psC[s] = ps2;
        if (lane == 63) { lds_tot[wv][s] = ps; lds_tot[wv][8 + s] = ps2; }
    }
    __syncthreads();
    if (wv == 0 && lane < 16) {
        int t0 = lds_tot[0][lane], t1 = lds_tot[1][lane],
            t2 = lds_tot[2][lane], t3 = lds_tot[3][lane];
        int gb = atomicAdd(&gcur[lane * 32], t0 + t1 + t2 + t3);  // 16 lines in parallel
        lds_base[0][lane] = gb;
        lds_base[1][lane] = gb + t0;
        lds_base[2][lane] = gb + t0 + t1;
        lds_base[3][lane] = gb + t0 + t1 + t2;
    }
    __syncthreads();

    if (n < N) {
        u64 dpR = 0, dpC = 0;
        int tr = 0, tc = 0;
        #pragma unroll
        for (int s = 0; s < SH; ++s) {
            curR[(size_t)s * N + n] = s * SH_SZ + lds_base[wv][s]     + psR[s] - cr[s];
            curC[(size_t)s * N + n] = s * SH_SZ + lds_base[wv][8 + s] + psC[s] - cc[s];
            dpR |= ((u64)cr[s]) << (8 * s); tr += cr[s];
            dpC |= ((u64)cc[s]) << (8 * s); tc += cc[s];
        }
        degpackR[n] = dpR;
        degpackC[n] = dpC;
        const u64 M27 = (1ULL << 27) - 1;
        const float qs = 1.0f / 65536.0f;
        float sr0 = (float)((TR >> 27) & M27) * qs;
        float sr1 = (float)(TR & M27) * qs;
        float sc0 = (float)((TC >> 27) & M27) * qs;
        float sc1 = (float)(TC & M27) * qs;
        float ir = 1.0f / fmaxf((float)tr, 1.0f);
        float ic = 1.0f / fmaxf((float)tc, 1.0f);
        float* sN = stats + (size_t)n * 8;
        sN[0] = ir;        sN[1] = ic;
        sN[2] = sr0 * ir;  sN[3] = sr1 * ir;
        sN[4] = sc0 * ic;  sN[5] = sc1 * ic;
        sN[6] = (float)tr; sN[7] = (float)tc;
    }
}

// ---------------------------------------------------------------------------
// K3: sharded bucket fill — cursors and staging region XCD-local.
// ---------------------------------------------------------------------------
__global__ __launch_bounds__(256) void k_fill(
    const int* __restrict__ row, const int* __restrict__ col,
    int* __restrict__ curR, int* __restrict__ curC,
    int* __restrict__ stageR, int* __restrict__ stageC, int E, int N, int SH_SZ)
{
    int s = blockIdx.x & (SH - 1);
    int j = blockIdx.x >> 3;
    int ebase = s * SH_SZ;
    int ssz = min(SH_SZ, E - ebase);
    int idx = j * 256 + threadIdx.x;
    if (idx >= ssz) return;
    int e = ebase + idx;
    int r = row[e], c = col[e];
    stageR[atomicAdd(&curR[(size_t)s * N + r], 1)] = c;
    stageC[atomicAdd(&curC[(size_t)s * N + c], 1)] = r;
}

// ---------------------------------------------------------------------------
// 8-segment gather: branchless prefix-select over shards.
// post-fill cur[s][n] = seg_start + deg  ->  start = cur - deg.
// ---------------------------------------------------------------------------
__device__ __forceinline__ float4 gather_side(
    const int* __restrict__ stage, const int* __restrict__ cur, u64 dp,
    int n, int N, const float4* __restrict__ x4, int grp, int c4)
{
    int d[SH], p[SH], st[SH];
    #pragma unroll
    for (int s = 0; s < SH; ++s) d[s] = (int)((dp >> (8 * s)) & 255);
    p[0] = 0;
    #pragma unroll
    for (int s = 1; s < SH; ++s) p[s] = p[s - 1] + d[s - 1];
    int deg = p[SH - 1] + d[SH - 1];
    #pragma unroll
    for (int s = 0; s < SH; ++s)
        st[s] = cur[(size_t)s * N + n] - d[s] - p[s];

    float4 acc = make_float4(0.f, 0.f, 0.f, 0.f);
    for (int k = 0; k < deg; k += 4) {
        int kk = k + grp;
        int addr = st[0] + kk;
        #pragma unroll
        for (int s = 1; s < SH; ++s)
            addr = (kk >= p[s]) ? st[s] + kk : addr;
        bool pv = kk < deg;
        int a = stage[pv ? addr : 0];
        float4 v = x4[(size_t)a * 16 + c4];
        if (pv) { acc.x += v.x; acc.y += v.y; acc.z += v.z; acc.w += v.w; }
    }
    return acc;
}

// ---------------------------------------------------------------------------
// K4: fused layer. 512 threads, 16 nodes/block, 2 nodes/wave; float4 gathers
// (4 neighbors per wave-instr), cross-group shfl reduce, h[128] @ W + rank-2
// opinion epilogue. LDS 40KB -> 32 waves/CU.
// ---------------------------------------------------------------------------
__global__ __launch_bounds__(512) void k_layer(
    const float* __restrict__ x,
    const int* __restrict__ curR, const int* __restrict__ curC,
    const int* __restrict__ stageR, const int* __restrict__ stageC,
    const u64* __restrict__ degpackR, const u64* __restrict__ degpackC,
    const float* __restrict__ stats,
    const float* __restrict__ Ttw,   // [4][64]
    const float* __restrict__ W,     // [256][64]
    const float* __restrict__ b,     // [64]
    float* __restrict__ y, int N)
{
    __shared__ float4 hs4[16][32];
    __shared__ float  Ws[128 * 64];

    const float4* x4 = (const float4*)x;

    int t    = threadIdx.x;
    int lane = t & 63;
    int wv   = t >> 6;
    int c4   = lane & 15;
    int grp  = lane >> 4;
    int base = blockIdx.x * 16;

    float sf[2][4];

    #pragma unroll
    for (int i = 0; i < 2; ++i) {
        int loc = wv * 2 + i;
        int n   = base + loc;
        float4 accR = make_float4(0.f, 0.f, 0.f, 0.f);
        float4 accC = make_float4(0.f, 0.f, 0.f, 0.f);
        float ir = 0.f, ic = 0.f;
        sf[i][0] = sf[i][1] = sf[i][2] = sf[i][3] = 0.f;
        if (n < N) {
            const float4* st = (const float4*)(stats + (size_t)n * 8);
            float4 sA = st[0];
            float4 sB = st[1];
            ir = sA.x; ic = sA.y;
            sf[i][0] = sA.z; sf[i][1] = sA.w;
            sf[i][2] = sB.x; sf[i][3] = sB.y;
            accR = gather_side(stageR, curR, degpackR[n], n, N, x4, grp, c4);
            accC = gather_side(stageC, curC, degpackC[n], n, N, x4, grp, c4);
        }
        #pragma unroll
        for (int o = 16; o < 64; o <<= 1) {
            accR.x += __shfl_xor(accR.x, o); accR.y += __shfl_xor(accR.y, o);
            accR.z += __shfl_xor(accR.z, o); accR.w += __shfl_xor(accR.w, o);
            accC.x += __shfl_xor(accC.x, o); accC.y += __shfl_xor(accC.y, o);
            accC.z += __shfl_xor(accC.z, o); accC.w += __shfl_xor(accC.w, o);
        }
        if (grp == 0) {
            hs4[loc][c4]      = make_float4(accR.x * ir, accR.y * ir, accR.z * ir, accR.w * ir);
            hs4[loc][16 + c4] = make_float4(accC.x * ic, accC.y * ic, accC.z * ic, accC.w * ic);
        }
    }

    __syncthreads();
    #pragma unroll
    for (int i = 0; i < 16; ++i) {
        int L = i * 512 + t;
        Ws[L] = W[L + ((L < 4096) ? 0 : 4096)];
    }
    __syncthreads();

    const float* hsf = (const float*)hs4;
    int r0 = (wv * 2) * 128, r1 = r0 + 128;
    float a0 = 0.f, a1 = 0.f;
    #pragma unroll 8
    for (int j = 0; j < 128; ++j) {
        float wj = Ws[j * 64 + lane];
        a0 += hsf[r0 + j] * wj;
        a1 += hsf[r1 + j] * wj;
    }

    float tR0 = Ttw[lane],       tR1 = Ttw[64 + lane];
    float tC0 = Ttw[128 + lane], tC1 = Ttw[192 + lane];
    float bias = b[lane];
    float vv[2] = {a0, a1};
    #pragma unroll
    for (int i = 0; i < 2; ++i) {
        int n = base + wv * 2 + i;
        if (n < N) {
            float v = vv[i] + sf[i][0] * tR0 + sf[i][1] * tR1
                            + sf[i][2] * tC0 + sf[i][3] * tC1 + bias;
            y[(size_t)n * D + lane] = fmaxf(v, 0.0f);
        }
    }
}

// ---------------------------------------------------------------------------
extern "C" void kernel_launch(void* const* d_in, const int* in_sizes, int n_in,
                              void* d_out, int out_size, void* d_ws, size_t ws_size,
                              hipStream_t stream)
{
    const float* X   = (const float*)d_in[0];
    const int*   ei  = (const int*)  d_in[1];
    const float* el  = (const float*)d_in[2];
    const float* w1  = (const float*)d_in[3];
    const float* tw1 = (const float*)d_in[4];
    const float* b1  = (const float*)d_in[5];
    const float* w2  = (const float*)d_in[6];
    const float* tw2 = (const float*)d_in[7];
    const float* b2  = (const float*)d_in[8];
    float* out = (float*)d_out;

    int N = in_sizes[0] / D;     // 50000
    int E = in_sizes[1] / 2;     // 800000
    const int* row = ei;
    const int* col = ei + E;
    int SH_SZ = (E + SH - 1) / SH;

    // Workspace (~24.8 MB). pack region reused as staging CSR after k_prep.
    size_t packBytes = (size_t)2 * SH * N * sizeof(u64);
    size_t stageBytes = (size_t)2 * E * sizeof(int);
    if (stageBytes > packBytes) packBytes = stageBytes;

    char* wsb = (char*)d_ws;
    u64*   packR    = (u64*)wsb;                        // SH*N u64 (zeroed)
    u64*   packC    = packR + (size_t)SH * N;           // SH*N u64 (zeroed)
    int*   stageR   = (int*)wsb;                        // E ints (aliases pack)
    int*   stageC   = stageR + E;                       // E ints
    int*   gcur     = (int*)(wsb + packBytes);          // 512 ints, line-padded (zeroed)
    int*   curR     = gcur + 512;                       // SH*N
    int*   curC     = curR + (size_t)SH * N;            // SH*N
    u64*   degpackR = (u64*)(curC + (size_t)SH * N);    // N
    u64*   degpackC = degpackR + N;                     // N
    float* stats    = (float*)(degpackC + N);           // 8N
    float* Ttw1     = stats + (size_t)8 * N;            // 256
    float* Ttw2     = Ttw1 + 256;                       // 256
    float* h1       = Ttw2 + 256;                       // 64N

    (void)hipMemsetAsync(packR, 0, (size_t)2 * SH * N * sizeof(u64), stream);
    (void)hipMemsetAsync(gcur, 0, 512 * sizeof(int), stream);

    k_ttw<<<2, 256, 0, stream>>>(tw1, w1, Ttw1, tw2, w2, Ttw2);

    int SB = SH * ((SH_SZ + 255) / 256);
    int NB = (N + 255) / 256;
    int LB = (N + 15) / 16;

    k_count<<<SB, 256, 0, stream>>>(row, col, el, packR, packC, E, N, SH_SZ);
    k_prep<<<NB, 256, 0, stream>>>(packR, packC, curR, curC,
                                   degpackR, degpackC, stats, gcur, N, SH_SZ);
    k_fill<<<SB, 256, 0, stream>>>(row, col, curR, curC, stageR, stageC, E, N, SH_SZ);

    k_layer<<<LB, 512, 0, stream>>>(X, curR, curC, stageR, stageC,
                                    degpackR, degpackC, stats,
                                    Ttw1, w1, b1, h1, N);
    k_layer<<<LB, 512, 0, stream>>>(h1, curR, curC, stageR, stageC,
                                    degpackR, degpackC, stats,
                                    Ttw2, w2, b2, out, N);
}